// Round 1
// baseline (705.512 us; speedup 1.0000x reference)
//
#include <hip/hip_runtime.h>
#include <hip/hip_bf16.h>

// GraphSAGE 2-layer, fp32. Strategy:
//   1. Build CSR-by-dst (deg histogram -> exclusive scan -> bucket fill).
//   2. One wave per node: lane = feature dim; register-accumulate neighbor
//      rows (coalesced 256B reads, no atomics), then fused matvec via LDS.
// d_ws layout: deg[N] | offsets[N+1] | cursor[N] | esrc[E] | pad | h[N*64]

__global__ void k_zero(int* __restrict__ p, int n) {
    int i = blockIdx.x * blockDim.x + threadIdx.x;
    if (i < n) p[i] = 0;
}

__global__ void k_hist(const int* __restrict__ dst, int* __restrict__ deg, int e) {
    int i = blockIdx.x * blockDim.x + threadIdx.x;
    if (i < e) atomicAdd(&deg[dst[i]], 1);
}

#define SCAN_THREADS 1024
__global__ void k_scan(const int* __restrict__ deg, int* __restrict__ offsets,
                       int* __restrict__ cursor, int n) {
    __shared__ int part[SCAN_THREADS];
    int t = threadIdx.x;
    int per = (n + SCAN_THREADS - 1) / SCAN_THREADS;
    int start = t * per;
    int end = start + per; if (end > n) end = n;
    int s = 0;
    for (int i = start; i < end; ++i) s += deg[i];
    part[t] = s;
    __syncthreads();
    // Hillis-Steele inclusive scan over 1024 partials
    for (int off = 1; off < SCAN_THREADS; off <<= 1) {
        int v = (t >= off) ? part[t - off] : 0;
        __syncthreads();
        part[t] += v;
        __syncthreads();
    }
    int run = (t == 0) ? 0 : part[t - 1];
    for (int i = start; i < end; ++i) {
        offsets[i] = run;
        cursor[i]  = run;
        run += deg[i];
    }
    if (start < n && end == n) offsets[n] = run;
}

__global__ void k_fill(const int* __restrict__ src, const int* __restrict__ dst,
                       int* __restrict__ cursor, int* __restrict__ esrc, int e) {
    int i = blockIdx.x * blockDim.x + threadIdx.x;
    if (i < e) {
        int d = dst[i];
        int p = atomicAdd(&cursor[d], 1);
        esrc[p] = src[i];
    }
}

// One wave (64 lanes) per node. Lane = input feature dim (D_IN == 64).
// DOUT: output dim (64 layer1, 32 layer2). RELU applied for layer1.
template <int DOUT, bool RELU>
__global__ __launch_bounds__(256) void k_sage_layer(
    const float* __restrict__ x,        // [n, 64]
    const int*   __restrict__ offsets,  // [n+1]
    const int*   __restrict__ esrc,     // [E] src ids bucketed by dst
    const float* __restrict__ wself,    // [64, DOUT]
    const float* __restrict__ wneigh,   // [64, DOUT]
    const float* __restrict__ bias,     // [DOUT]
    float* __restrict__ out,            // [n, DOUT]
    int n)
{
    constexpr int WAVES = 4;
    __shared__ float sWs[64 * DOUT];
    __shared__ float sWn[64 * DOUT];
    __shared__ float sX[WAVES][64];
    __shared__ float sM[WAVES][64];

    // cooperative weight staging
    for (int i = threadIdx.x; i < 64 * DOUT; i += 256) {
        sWs[i] = wself[i];
        sWn[i] = wneigh[i];
    }

    const int w    = threadIdx.x >> 6;
    const int lane = threadIdx.x & 63;
    const int v    = blockIdx.x * WAVES + w;

    if (v < n) {
        const int beg = offsets[v], end = offsets[v + 1];
        float acc = 0.f;
        int e = beg;
        // unroll-by-4: batch the edge-id loads and row gathers for ILP
        for (; e + 4 <= end; e += 4) {
            int s0 = esrc[e + 0], s1 = esrc[e + 1], s2 = esrc[e + 2], s3 = esrc[e + 3];
            float a0 = x[(size_t)s0 * 64 + lane];
            float a1 = x[(size_t)s1 * 64 + lane];
            float a2 = x[(size_t)s2 * 64 + lane];
            float a3 = x[(size_t)s3 * 64 + lane];
            acc += (a0 + a1) + (a2 + a3);
        }
        for (; e < end; ++e) acc += x[(size_t)esrc[e] * 64 + lane];
        const int deg = end - beg;
        const float mean = (deg > 0) ? acc / (float)deg : 0.f;
        sX[w][lane] = x[(size_t)v * 64 + lane];
        sM[w][lane] = mean;
    }
    __syncthreads();  // weights staged + fragments written

    if (v < n && lane < DOUT) {
        float acc2 = bias[lane];
        #pragma unroll
        for (int i = 0; i < 64; ++i) {
            acc2 += sX[w][i] * sWs[i * DOUT + lane];   // sX broadcast: free
            acc2 += sM[w][i] * sWn[i * DOUT + lane];   // stride-DOUT: <=2-way, free
        }
        if (RELU) acc2 = fmaxf(acc2, 0.f);
        out[(size_t)v * DOUT + lane] = acc2;
    }
}

extern "C" void kernel_launch(void* const* d_in, const int* in_sizes, int n_in,
                              void* d_out, int out_size, void* d_ws, size_t ws_size,
                              hipStream_t stream) {
    const float* feat = (const float*)d_in[0];
    const int*   src  = (const int*)d_in[1];
    const int*   dst  = (const int*)d_in[2];
    const float* ws1  = (const float*)d_in[3];
    const float* wn1  = (const float*)d_in[4];
    const float* b1   = (const float*)d_in[5];
    const float* ws2  = (const float*)d_in[6];
    const float* wn2  = (const float*)d_in[7];
    const float* b2   = (const float*)d_in[8];
    float* out = (float*)d_out;

    const int N = in_sizes[0] / 64;
    const int E = in_sizes[1];

    char* base = (char*)d_ws;
    int* deg     = (int*)base;          // [N]
    int* offsets = deg + N;             // [N+1]
    int* cursor  = offsets + (N + 1);   // [N]
    int* esrc    = cursor + N;          // [E]
    size_t hOff = (((size_t)(3 * N + 1 + E) * 4) + 255) & ~(size_t)255;
    float* h = (float*)(base + hOff);   // [N, 64]

    // CSR build
    k_zero<<<(N + 255) / 256, 256, 0, stream>>>(deg, N);
    k_hist<<<(E + 255) / 256, 256, 0, stream>>>(dst, deg, E);
    k_scan<<<1, SCAN_THREADS, 0, stream>>>(deg, offsets, cursor, N);
    k_fill<<<(E + 255) / 256, 256, 0, stream>>>(src, dst, cursor, esrc, E);

    // two fused aggregate+transform layers
    const int blocks = (N + 3) / 4;
    k_sage_layer<64, true ><<<blocks, 256, 0, stream>>>(feat, offsets, esrc, ws1, wn1, b1, h, N);
    k_sage_layer<32, false><<<blocks, 256, 0, stream>>>(h,    offsets, esrc, ws2, wn2, b2, out, N);
}

// Round 2
// 481.944 us; speedup vs baseline: 1.4639x; 1.4639x over previous
//
#include <hip/hip_runtime.h>
#include <hip/hip_bf16.h>

// GraphSAGE 2-layer, fp32.
//   1. Build CSR-by-dst (deg histogram -> 3-pass parallel exclusive scan ->
//      bucket fill).
//   2. One wave per node: lane = feature dim; register-accumulate neighbor
//      rows (coalesced 256B reads, no atomics), then fused matvec via LDS.
// d_ws: deg[N] | offsets[N+1] | cursor[N] | esrc[E] | blockSums[256] |
//       blockPrefix[256] | pad | h[N*64]

__global__ void k_zero(int* __restrict__ p, int n) {
    int i = blockIdx.x * blockDim.x + threadIdx.x;
    if (i < n) p[i] = 0;
}

__global__ void k_hist(const int* __restrict__ dst, int* __restrict__ deg, int e) {
    int i = blockIdx.x * blockDim.x + threadIdx.x;
    if (i < e) atomicAdd(&deg[dst[i]], 1);
}

#define NB_SCAN 256

// Pass A: per-block local exclusive scan into offsets[], block total out.
__global__ __launch_bounds__(256) void k_scan_a(const int* __restrict__ deg,
                                                int* __restrict__ offsets,
                                                int* __restrict__ blockSums, int n) {
    __shared__ int part[256];
    const int b = blockIdx.x, t = threadIdx.x;
    const int chunk  = (n + NB_SCAN - 1) / NB_SCAN;
    const int bstart = b * chunk;
    const int bend   = min(bstart + chunk, n);
    const int per    = (chunk + 255) / 256;
    const int start  = bstart + t * per;
    const int end    = min(start + per, bend);
    int s = 0;
    for (int i = start; i < end; ++i) s += deg[i];
    part[t] = s;
    __syncthreads();
    for (int off = 1; off < 256; off <<= 1) {
        int v = (t >= off) ? part[t - off] : 0;
        __syncthreads();
        part[t] += v;
        __syncthreads();
    }
    int run = (t == 0) ? 0 : part[t - 1];
    for (int i = start; i < end; ++i) { offsets[i] = run; run += deg[i]; }
    if (t == 255) blockSums[b] = part[255];
}

// Pass B: scan the 256 block sums; also write grand total to offsets[n].
__global__ __launch_bounds__(NB_SCAN) void k_scan_b(const int* __restrict__ blockSums,
                                                    int* __restrict__ blockPrefix,
                                                    int* __restrict__ offsets, int n) {
    __shared__ int part[NB_SCAN];
    const int t = threadIdx.x;
    part[t] = blockSums[t];
    __syncthreads();
    for (int off = 1; off < NB_SCAN; off <<= 1) {
        int v = (t >= off) ? part[t - off] : 0;
        __syncthreads();
        part[t] += v;
        __syncthreads();
    }
    blockPrefix[t] = (t == 0) ? 0 : part[t - 1];
    if (t == NB_SCAN - 1) offsets[n] = part[NB_SCAN - 1];
}

// Pass C: add block prefix; mirror into cursor[].
__global__ __launch_bounds__(256) void k_scan_c(int* __restrict__ offsets,
                                                int* __restrict__ cursor,
                                                const int* __restrict__ blockPrefix, int n) {
    const int b = blockIdx.x;
    const int chunk  = (n + NB_SCAN - 1) / NB_SCAN;
    const int bstart = b * chunk;
    const int bend   = min(bstart + chunk, n);
    const int p = blockPrefix[b];
    for (int i = bstart + threadIdx.x; i < bend; i += 256) {
        int v = offsets[i] + p;
        offsets[i] = v;
        cursor[i]  = v;
    }
}

__global__ void k_fill(const int* __restrict__ src, const int* __restrict__ dst,
                       int* __restrict__ cursor, int* __restrict__ esrc, int e) {
    int i = blockIdx.x * blockDim.x + threadIdx.x;
    if (i < e) {
        int d = dst[i];
        int p = atomicAdd(&cursor[d], 1);
        esrc[p] = src[i];
    }
}

// One wave (64 lanes) per node. Lane = input feature dim (D_IN == 64).
template <int DOUT, bool RELU>
__global__ __launch_bounds__(256) void k_sage_layer(
    const float* __restrict__ x,        // [n, 64]
    const int*   __restrict__ offsets,  // [n+1]
    const int*   __restrict__ esrc,     // [E] src ids bucketed by dst
    const float* __restrict__ wself,    // [64, DOUT]
    const float* __restrict__ wneigh,   // [64, DOUT]
    const float* __restrict__ bias,     // [DOUT]
    float* __restrict__ out,            // [n, DOUT]
    int n)
{
    constexpr int WAVES = 4;
    __shared__ float sWs[64 * DOUT];
    __shared__ float sWn[64 * DOUT];
    __shared__ float sX[WAVES][64];
    __shared__ float sM[WAVES][64];

    for (int i = threadIdx.x; i < 64 * DOUT; i += 256) {
        sWs[i] = wself[i];
        sWn[i] = wneigh[i];
    }

    const int w    = threadIdx.x >> 6;
    const int lane = threadIdx.x & 63;
    const int v    = blockIdx.x * WAVES + w;

    if (v < n) {
        const int beg = offsets[v], end = offsets[v + 1];
        float acc = 0.f;
        int e = beg;
        for (; e + 4 <= end; e += 4) {
            int s0 = esrc[e + 0], s1 = esrc[e + 1], s2 = esrc[e + 2], s3 = esrc[e + 3];
            float a0 = x[(size_t)s0 * 64 + lane];
            float a1 = x[(size_t)s1 * 64 + lane];
            float a2 = x[(size_t)s2 * 64 + lane];
            float a3 = x[(size_t)s3 * 64 + lane];
            acc += (a0 + a1) + (a2 + a3);
        }
        for (; e < end; ++e) acc += x[(size_t)esrc[e] * 64 + lane];
        const int deg = end - beg;
        const float mean = (deg > 0) ? acc / (float)deg : 0.f;
        sX[w][lane] = x[(size_t)v * 64 + lane];
        sM[w][lane] = mean;
    }
    __syncthreads();

    if (v < n && lane < DOUT) {
        float acc2 = bias[lane];
        #pragma unroll
        for (int i = 0; i < 64; ++i) {
            acc2 += sX[w][i] * sWs[i * DOUT + lane];
            acc2 += sM[w][i] * sWn[i * DOUT + lane];
        }
        if (RELU) acc2 = fmaxf(acc2, 0.f);
        out[(size_t)v * DOUT + lane] = acc2;
    }
}

extern "C" void kernel_launch(void* const* d_in, const int* in_sizes, int n_in,
                              void* d_out, int out_size, void* d_ws, size_t ws_size,
                              hipStream_t stream) {
    const float* feat = (const float*)d_in[0];
    const int*   src  = (const int*)d_in[1];
    const int*   dst  = (const int*)d_in[2];
    const float* ws1  = (const float*)d_in[3];
    const float* wn1  = (const float*)d_in[4];
    const float* b1   = (const float*)d_in[5];
    const float* ws2  = (const float*)d_in[6];
    const float* wn2  = (const float*)d_in[7];
    const float* b2   = (const float*)d_in[8];
    float* out = (float*)d_out;

    const int N = in_sizes[0] / 64;
    const int E = in_sizes[1];

    char* base = (char*)d_ws;
    int* deg         = (int*)base;              // [N]
    int* offsets     = deg + N;                 // [N+1]
    int* cursor      = offsets + (N + 1);       // [N]
    int* esrc        = cursor + N;              // [E]
    int* blockSums   = esrc + E;                // [256]
    int* blockPrefix = blockSums + NB_SCAN;     // [256]
    size_t hOff = (((size_t)(3 * N + 1 + E + 2 * NB_SCAN) * 4) + 255) & ~(size_t)255;
    float* h = (float*)(base + hOff);           // [N, 64]

    // CSR build
    k_zero<<<(N + 255) / 256, 256, 0, stream>>>(deg, N);
    k_hist<<<(E + 255) / 256, 256, 0, stream>>>(dst, deg, E);
    k_scan_a<<<NB_SCAN, 256, 0, stream>>>(deg, offsets, blockSums, N);
    k_scan_b<<<1, NB_SCAN, 0, stream>>>(blockSums, blockPrefix, offsets, N);
    k_scan_c<<<NB_SCAN, 256, 0, stream>>>(offsets, cursor, blockPrefix, N);
    k_fill<<<(E + 255) / 256, 256, 0, stream>>>(src, dst, cursor, esrc, E);

    // two fused aggregate+transform layers
    const int blocks = (N + 3) / 4;
    k_sage_layer<64, true ><<<blocks, 256, 0, stream>>>(feat, offsets, esrc, ws1, wn1, b1, h, N);
    k_sage_layer<32, false><<<blocks, 256, 0, stream>>>(h,    offsets, esrc, ws2, wn2, b2, out, N);
}

// Round 3
// 380.223 us; speedup vs baseline: 1.8555x; 1.2675x over previous
//
#include <hip/hip_runtime.h>
#include <hip/hip_bf16.h>

// GraphSAGE 2-layer, fp32.
//   CSR build (hist -> 3-pass scan -> fill), then per layer:
//     k_gather_mean : one wave per node, register-accumulate neighbor rows
//     k_gemm        : out = X@Ws + M@Wn + b  (128-node tile, LDS-staged,
//                     8x4 micro-tile per thread -> 32 FMA per 3 ds_read_b128)
// Splitting gather from transform removes the per-node weight re-read from
// LDS that dominated the fused kernel (128 ds_read_b32/lane/node).
// d_ws: deg|cursor[N] (aliased) | offsets[N+1] | esrc[E] | blockSums[256] |
//       blockPrefix[256] | pad | mean[N*64] | h[N*64]

__global__ void k_zero(int* __restrict__ p, int n) {
    int i = blockIdx.x * blockDim.x + threadIdx.x;
    if (i < n) p[i] = 0;
}

__global__ void k_hist(const int* __restrict__ dst, int* __restrict__ deg, int e) {
    int i = blockIdx.x * blockDim.x + threadIdx.x;
    if (i < e) atomicAdd(&deg[dst[i]], 1);
}

#define NB_SCAN 256

__global__ __launch_bounds__(256) void k_scan_a(const int* __restrict__ deg,
                                                int* __restrict__ offsets,
                                                int* __restrict__ blockSums, int n) {
    __shared__ int part[256];
    const int b = blockIdx.x, t = threadIdx.x;
    const int chunk  = (n + NB_SCAN - 1) / NB_SCAN;
    const int bstart = b * chunk;
    const int bend   = min(bstart + chunk, n);
    const int per    = (chunk + 255) / 256;
    const int start  = bstart + t * per;
    const int end    = min(start + per, bend);
    int s = 0;
    for (int i = start; i < end; ++i) s += deg[i];
    part[t] = s;
    __syncthreads();
    for (int off = 1; off < 256; off <<= 1) {
        int v = (t >= off) ? part[t - off] : 0;
        __syncthreads();
        part[t] += v;
        __syncthreads();
    }
    int run = (t == 0) ? 0 : part[t - 1];
    for (int i = start; i < end; ++i) { offsets[i] = run; run += deg[i]; }
    if (t == 255) blockSums[b] = part[255];
}

__global__ __launch_bounds__(NB_SCAN) void k_scan_b(const int* __restrict__ blockSums,
                                                    int* __restrict__ blockPrefix,
                                                    int* __restrict__ offsets, int n) {
    __shared__ int part[NB_SCAN];
    const int t = threadIdx.x;
    part[t] = blockSums[t];
    __syncthreads();
    for (int off = 1; off < NB_SCAN; off <<= 1) {
        int v = (t >= off) ? part[t - off] : 0;
        __syncthreads();
        part[t] += v;
        __syncthreads();
    }
    blockPrefix[t] = (t == 0) ? 0 : part[t - 1];
    if (t == NB_SCAN - 1) offsets[n] = part[NB_SCAN - 1];
}

__global__ __launch_bounds__(256) void k_scan_c(int* __restrict__ offsets,
                                                int* __restrict__ cursor,
                                                const int* __restrict__ blockPrefix, int n) {
    const int b = blockIdx.x;
    const int chunk  = (n + NB_SCAN - 1) / NB_SCAN;
    const int bstart = b * chunk;
    const int bend   = min(bstart + chunk, n);
    const int p = blockPrefix[b];
    for (int i = bstart + threadIdx.x; i < bend; i += 256) {
        int v = offsets[i] + p;
        offsets[i] = v;
        cursor[i]  = v;
    }
}

__global__ void k_fill(const int* __restrict__ src, const int* __restrict__ dst,
                       int* __restrict__ cursor, int* __restrict__ esrc, int e) {
    int i = blockIdx.x * blockDim.x + threadIdx.x;
    if (i < e) {
        int d = dst[i];
        int p = atomicAdd(&cursor[d], 1);
        esrc[p] = src[i];
    }
}

// One wave per node, lane = feature dim. Pure mean aggregation.
__global__ __launch_bounds__(256) void k_gather_mean(
    const float* __restrict__ x,        // [n, 64]
    const int*   __restrict__ offsets,  // [n+1]
    const int*   __restrict__ esrc,     // [E]
    float* __restrict__ mean,           // [n, 64]
    int n)
{
    const int w = threadIdx.x >> 6, lane = threadIdx.x & 63;
    const int v = blockIdx.x * 4 + w;
    if (v >= n) return;
    const int beg = offsets[v], end = offsets[v + 1];
    float acc = 0.f;
    int e = beg;
    for (; e + 8 <= end; e += 8) {
        int s0 = esrc[e+0], s1 = esrc[e+1], s2 = esrc[e+2], s3 = esrc[e+3];
        int s4 = esrc[e+4], s5 = esrc[e+5], s6 = esrc[e+6], s7 = esrc[e+7];
        float a0 = x[(size_t)s0*64+lane], a1 = x[(size_t)s1*64+lane];
        float a2 = x[(size_t)s2*64+lane], a3 = x[(size_t)s3*64+lane];
        float a4 = x[(size_t)s4*64+lane], a5 = x[(size_t)s5*64+lane];
        float a6 = x[(size_t)s6*64+lane], a7 = x[(size_t)s7*64+lane];
        acc += ((a0+a1)+(a2+a3)) + ((a4+a5)+(a6+a7));
    }
    for (; e < end; ++e) acc += x[(size_t)esrc[e]*64 + lane];
    const int deg = end - beg;
    mean[(size_t)v*64 + lane] = deg ? acc / (float)deg : 0.f;
}

// out[gm, c] = sum_k A0[gm,k]*W0[k,c] + A1[gm,k]*W1[k,c] + bias[c]
// Tile: 128 nodes x DOUT. 256 threads, each computes 8 rows x NT cols.
template <int DOUT, bool RELU>
__global__ __launch_bounds__(256) void k_gemm(
    const float* __restrict__ A0,   // [n,64]
    const float* __restrict__ A1,   // [n,64]
    const float* __restrict__ W0,   // [64,DOUT]
    const float* __restrict__ W1,   // [64,DOUT]
    const float* __restrict__ bias, // [DOUT]
    float* __restrict__ out,        // [n,DOUT]
    int n)
{
    constexpr int TM  = 128;
    constexpr int LDA = TM + 4;      // 132: keeps float4 16B alignment per k-row
    constexpr int LDW = DOUT + 4;
    constexpr int NT  = DOUT / 16;   // 4 (DOUT=64) or 2 (DOUT=32)
    __shared__ float sA[64 * LDA];
    __shared__ float sW[64 * LDW];

    const int tid = threadIdx.x;
    const int cg  = tid & 15;        // 16 col groups
    const int mg  = tid >> 4;        // 16 row groups
    const int m0  = mg * 8;
    const int c0  = cg * NT;
    const int gm0 = blockIdx.x * TM;

    float acc[8][NT];
    #pragma unroll
    for (int i = 0; i < 8; ++i)
        #pragma unroll
        for (int j = 0; j < NT; ++j) acc[i][j] = 0.f;

    #pragma unroll
    for (int half = 0; half < 2; ++half) {
        const float* __restrict__ A = half ? A1 : A0;
        const float* __restrict__ W = half ? W1 : W0;

        // stage W[k][c] -> sW (row-major, padded)
        for (int i = tid; i < 64 * (DOUT / 4); i += 256) {
            int k  = i / (DOUT / 4);
            int c4 = (i % (DOUT / 4)) * 4;
            float4 vv = *(const float4*)&W[k * DOUT + c4];
            *(float4*)&sW[k * LDW + c4] = vv;
        }
        // stage A transposed: sA[k][m]  (coalesced float4 global reads)
        for (int i = tid; i < TM * 16; i += 256) {
            int m  = i >> 4;
            int k4 = (i & 15) << 2;
            int gm = gm0 + m;
            float4 vv = make_float4(0.f, 0.f, 0.f, 0.f);
            if (gm < n) vv = *(const float4*)&A[(size_t)gm * 64 + k4];
            sA[(k4 + 0) * LDA + m] = vv.x;
            sA[(k4 + 1) * LDA + m] = vv.y;
            sA[(k4 + 2) * LDA + m] = vv.z;
            sA[(k4 + 3) * LDA + m] = vv.w;
        }
        __syncthreads();

        #pragma unroll 8
        for (int k = 0; k < 64; ++k) {
            float4 a0 = *(const float4*)&sA[k * LDA + m0];
            float4 a1 = *(const float4*)&sA[k * LDA + m0 + 4];
            float wv[NT];
            #pragma unroll
            for (int j = 0; j < NT; ++j) wv[j] = sW[k * LDW + c0 + j];
            float am[8] = {a0.x, a0.y, a0.z, a0.w, a1.x, a1.y, a1.z, a1.w};
            #pragma unroll
            for (int i = 0; i < 8; ++i)
                #pragma unroll
                for (int j = 0; j < NT; ++j)
                    acc[i][j] += am[i] * wv[j];
        }
        __syncthreads();
    }

    #pragma unroll
    for (int i = 0; i < 8; ++i) {
        int gm = gm0 + m0 + i;
        if (gm < n) {
            #pragma unroll
            for (int j = 0; j < NT; ++j) {
                float v = acc[i][j] + bias[c0 + j];
                if (RELU) v = fmaxf(v, 0.f);
                out[(size_t)gm * DOUT + c0 + j] = v;
            }
        }
    }
}

extern "C" void kernel_launch(void* const* d_in, const int* in_sizes, int n_in,
                              void* d_out, int out_size, void* d_ws, size_t ws_size,
                              hipStream_t stream) {
    const float* feat = (const float*)d_in[0];
    const int*   src  = (const int*)d_in[1];
    const int*   dst  = (const int*)d_in[2];
    const float* ws1  = (const float*)d_in[3];
    const float* wn1  = (const float*)d_in[4];
    const float* b1   = (const float*)d_in[5];
    const float* ws2  = (const float*)d_in[6];
    const float* wn2  = (const float*)d_in[7];
    const float* b2   = (const float*)d_in[8];
    float* out = (float*)d_out;

    const int N = in_sizes[0] / 64;
    const int E = in_sizes[1];

    char* base = (char*)d_ws;
    int* deg         = (int*)base;          // [N]; reused as cursor after scan
    int* cursor      = deg;
    int* offsets     = deg + N;             // [N+1]
    int* esrc        = offsets + (N + 1);   // [E]
    int* blockSums   = esrc + E;            // [256]
    int* blockPrefix = blockSums + NB_SCAN; // [256]
    size_t fOff = (((size_t)(2 * N + 1 + E + 2 * NB_SCAN) * 4) + 255) & ~(size_t)255;
    float* mean = (float*)(base + fOff);    // [N,64]; reused for layer-2 mean
    float* h    = mean + (size_t)N * 64;    // [N,64]

    // CSR build
    k_zero<<<(N + 255) / 256, 256, 0, stream>>>(deg, N);
    k_hist<<<(E + 255) / 256, 256, 0, stream>>>(dst, deg, E);
    k_scan_a<<<NB_SCAN, 256, 0, stream>>>(deg, offsets, blockSums, N);
    k_scan_b<<<1, NB_SCAN, 0, stream>>>(blockSums, blockPrefix, offsets, N);
    k_scan_c<<<NB_SCAN, 256, 0, stream>>>(offsets, cursor, blockPrefix, N);
    k_fill<<<(E + 255) / 256, 256, 0, stream>>>(src, dst, cursor, esrc, E);

    const int gblocks = (N + 3) / 4;
    const int tblocks = (N + 127) / 128;

    // layer 1
    k_gather_mean<<<gblocks, 256, 0, stream>>>(feat, offsets, esrc, mean, N);
    k_gemm<64, true ><<<tblocks, 256, 0, stream>>>(feat, mean, ws1, wn1, b1, h, N);
    // layer 2
    k_gather_mean<<<gblocks, 256, 0, stream>>>(h, offsets, esrc, mean, N);
    k_gemm<32, false><<<tblocks, 256, 0, stream>>>(h, mean, ws2, wn2, b2, out, N);
}